// Round 1
// baseline (80.978 us; speedup 1.0000x reference)
//
#include <hip/hip_runtime.h>
#include <hip/hip_bf16.h>

#define B_   4
#define N_   8192
#define CIN_ 64
#define D64_ 64
#define H_   8
#define HD_  512
#define NCH_ 64
#define EPS_ 1e-5f

typedef __bf16 bf16x8 __attribute__((ext_vector_type(8)));
typedef __bf16 bf16x4 __attribute__((ext_vector_type(4)));
typedef float  f32x4  __attribute__((ext_vector_type(4)));

// ---------------- workspace layout ----------------
constexpr size_t OFF_V    = 0;
constexpr size_t SZ_V     = (size_t)B_ * N_ * CIN_ * 2;        // 4 MB bf16 v
constexpr size_t OFF_WQ   = OFF_V + SZ_V;
constexpr size_t SZ_W     = (size_t)HD_ * CIN_ * 2;            // 64 KB each
constexpr size_t OFF_WK   = OFF_WQ + SZ_W;
constexpr size_t OFF_WV   = OFF_WK + SZ_W;
constexpr size_t OFF_MT   = OFF_WV + SZ_W;
constexpr size_t SZ_MT    = (size_t)B_ * 64 * HD_ * 2;         // 256 KB bf16 Mt
constexpr size_t OFF_PART = OFF_MT + SZ_MT;
constexpr size_t SZ_PART  = (size_t)B_ * H_ * NCH_ * 64 * 64 * 4; // 32 MB fp32
constexpr size_t OFF_KV   = OFF_PART + SZ_PART;
constexpr size_t SZ_KV    = (size_t)B_ * H_ * 64 * 64 * 4;     // 512 KB fp32
constexpr size_t WS_NEED  = OFF_KV + SZ_KV;

// ---------------- cast fp32 -> bf16 ----------------
__global__ void cast_f32_bf16(const float* __restrict__ src,
                              __bf16* __restrict__ dst, int n4) {
  int i = blockIdx.x * blockDim.x + threadIdx.x;
  if (i < n4) {
    const float4 f = reinterpret_cast<const float4*>(src)[i];
    bf16x4 o;
    o[0] = (__bf16)f.x; o[1] = (__bf16)f.y; o[2] = (__bf16)f.z; o[3] = (__bf16)f.w;
    reinterpret_cast<bf16x4*>(dst)[i] = o;
  }
}

// ---------------- helpers ----------------
// proj: acc[m][c] (16x16 tiles) = v_tile[64x64] @ W_head^T[64x64]
// A-frag: row = l15 (+m*16), k = kk*32 + g*8 .. +7 (contiguous).
// B-frag: col(out hd) = l15 (+c*16), same k mapping; W row-major [hd][cin].
__device__ __forceinline__ void proj16(const bf16x8 (&av)[4][2],
                                       const __bf16* __restrict__ w0,
                                       int l15, int g, f32x4 (&acc)[4][4]) {
  bf16x8 bf[4][2];
#pragma unroll
  for (int c = 0; c < 4; ++c)
#pragma unroll
    for (int kk = 0; kk < 2; ++kk)
      bf[c][kk] = *reinterpret_cast<const bf16x8*>(
          w0 + (size_t)(c * 16 + l15) * CIN_ + kk * 32 + g * 8);
#pragma unroll
  for (int m = 0; m < 4; ++m)
#pragma unroll
    for (int c = 0; c < 4; ++c) {
      f32x4 a = {0.f, 0.f, 0.f, 0.f};
      a = __builtin_amdgcn_mfma_f32_16x16x32_bf16(av[m][0], bf[c][0], a, 0, 0, 0);
      a = __builtin_amdgcn_mfma_f32_16x16x32_bf16(av[m][1], bf[c][1], a, 0, 0, 0);
      acc[m][c] = a;
    }
}

// LayerNorm over the head dim (64 cols) for acc[4][4] tiles in C/D layout:
// lane holds col = c*16+l15, rows = m*16 + g*4 + r. Row-sum = own 4 c-values
// then 16-lane butterfly (xor 1,2,4,8 stays inside the g-group).
__device__ __forceinline__ void ln_head(f32x4 (&acc)[4][4],
                                        const float (&lw)[4], const float (&lb)[4]) {
#pragma unroll
  for (int m = 0; m < 4; ++m) {
    float s[4] = {0.f, 0.f, 0.f, 0.f}, ss[4] = {0.f, 0.f, 0.f, 0.f};
#pragma unroll
    for (int c = 0; c < 4; ++c)
#pragma unroll
      for (int r = 0; r < 4; ++r) {
        float x = acc[m][c][r];
        s[r] += x; ss[r] += x * x;
      }
#pragma unroll
    for (int r = 0; r < 4; ++r) {
#pragma unroll
      for (int off = 1; off < 16; off <<= 1) {
        s[r]  += __shfl_xor(s[r], off);
        ss[r] += __shfl_xor(ss[r], off);
      }
      const float mu   = s[r] * (1.f / 64.f);
      const float var  = ss[r] * (1.f / 64.f) - mu * mu;
      const float rstd = rsqrtf(var + EPS_);
#pragma unroll
      for (int c = 0; c < 4; ++c)
        acc[m][c][r] = (acc[m][c][r] - mu) * rstd * lw[c] + lb[c];
    }
  }
}

// ---------------- K1: per-(b,h,chunk) KV partial ----------------
// 1 wave/block; chunk = 128 rows = 2 tiles of 64.
__global__ __launch_bounds__(64) void k1_kv(
    const __bf16* __restrict__ vb, const __bf16* __restrict__ wkb,
    const __bf16* __restrict__ wvb, const float* __restrict__ kbias,
    const float* __restrict__ vbias, const float* __restrict__ lnkw,
    const float* __restrict__ lnkb, float* __restrict__ part) {
  const int ch = blockIdx.x, h = blockIdx.y, b = blockIdx.z;
  const int lane = threadIdx.x;
  const int l15 = lane & 15, g = lane >> 4;
  __shared__ __bf16 Kt[64][72];  // [d][n], pad 72 -> 16B-aligned rows
  __shared__ __bf16 Vt[64][72];  // [e][n]

  const f32x4 z4 = {0.f, 0.f, 0.f, 0.f};
  f32x4 kv[4][4];
#pragma unroll
  for (int i = 0; i < 4; ++i)
#pragma unroll
    for (int j = 0; j < 4; ++j) kv[i][j] = z4;

  float kb[4], vbi[4], lw[4], lb[4];
#pragma unroll
  for (int c = 0; c < 4; ++c) {
    const int col = h * 64 + c * 16 + l15;
    kb[c] = kbias[col]; vbi[c] = vbias[col];
    lw[c] = lnkw[col];  lb[c] = lnkb[col];
  }

  for (int t = 0; t < 2; ++t) {
    const int row0 = ch * 128 + t * 64;
    bf16x8 av[4][2];
#pragma unroll
    for (int m = 0; m < 4; ++m)
#pragma unroll
      for (int kk = 0; kk < 2; ++kk)
        av[m][kk] = *reinterpret_cast<const bf16x8*>(
            vb + ((size_t)b * N_ + row0 + m * 16 + l15) * CIN_ + kk * 32 + g * 8);

    f32x4 acc[4][4];
    // K projection + bias + LN -> Kt (transposed: [d][n])
    proj16(av, wkb + (size_t)h * 64 * CIN_, l15, g, acc);
#pragma unroll
    for (int m = 0; m < 4; ++m)
#pragma unroll
      for (int c = 0; c < 4; ++c)
#pragma unroll
        for (int r = 0; r < 4; ++r) acc[m][c][r] += kb[c];
    ln_head(acc, lw, lb);
#pragma unroll
    for (int m = 0; m < 4; ++m)
#pragma unroll
      for (int c = 0; c < 4; ++c) {
        bf16x4 p;
#pragma unroll
        for (int r = 0; r < 4; ++r) p[r] = (__bf16)acc[m][c][r];
        *reinterpret_cast<bf16x4*>(&Kt[c * 16 + l15][m * 16 + g * 4]) = p;
      }

    // V projection + bias -> Vt
    proj16(av, wvb + (size_t)h * 64 * CIN_, l15, g, acc);
#pragma unroll
    for (int m = 0; m < 4; ++m)
#pragma unroll
      for (int c = 0; c < 4; ++c) {
        bf16x4 p;
#pragma unroll
        for (int r = 0; r < 4; ++r) p[r] = (__bf16)(acc[m][c][r] + vbi[c]);
        *reinterpret_cast<bf16x4*>(&Vt[c * 16 + l15][m * 16 + g * 4]) = p;
      }

    __syncthreads();

    // KV[d,e] += Kt(d,:) . Vt(e,:) over this tile's 64 n's
    bf16x8 va[4][2];
#pragma unroll
    for (int et = 0; et < 4; ++et)
#pragma unroll
      for (int nk = 0; nk < 2; ++nk)
        va[et][nk] = *reinterpret_cast<const bf16x8*>(&Vt[et * 16 + l15][nk * 32 + g * 8]);
#pragma unroll
    for (int dt = 0; dt < 4; ++dt) {
      bf16x8 ka[2];
#pragma unroll
      for (int nk = 0; nk < 2; ++nk)
        ka[nk] = *reinterpret_cast<const bf16x8*>(&Kt[dt * 16 + l15][nk * 32 + g * 8]);
#pragma unroll
      for (int et = 0; et < 4; ++et) {
        kv[dt][et] = __builtin_amdgcn_mfma_f32_16x16x32_bf16(ka[0], va[et][0], kv[dt][et], 0, 0, 0);
        kv[dt][et] = __builtin_amdgcn_mfma_f32_16x16x32_bf16(ka[1], va[et][1], kv[dt][et], 0, 0, 0);
      }
    }
    __syncthreads();
  }

  float* p0 = part + (size_t)((b * H_ + h) * NCH_ + ch) * 4096;
#pragma unroll
  for (int dt = 0; dt < 4; ++dt)
#pragma unroll
    for (int et = 0; et < 4; ++et)
#pragma unroll
      for (int r = 0; r < 4; ++r)
        p0[(dt * 16 + g * 4 + r) * 64 + et * 16 + l15] = kv[dt][et][r];
}

// ---------------- K2a: tree-reduce partials -> KV ----------------
__global__ __launch_bounds__(256) void k2a_reduce(const float* __restrict__ part,
                                                 float* __restrict__ KVg) {
  const int s = blockIdx.x, h = blockIdx.y, b = blockIdx.z;
  const int idx = s * 256 + threadIdx.x;
  const float* p0 = part + (size_t)((b * H_ + h) * NCH_) * 4096 + idx;
  float acc = 0.f;
#pragma unroll 8
  for (int ch = 0; ch < NCH_; ++ch) acc += p0[(size_t)ch * 4096];
  KVg[(size_t)(b * H_ + h) * 4096 + idx] = acc;
}

// ---------------- K2b: Mt[b][j][h*64+d] = (KV_h @ ow_h^T)[d,j] / N ----------------
__global__ __launch_bounds__(256) void k2b_mt(const float* __restrict__ KVg,
                                              const float* __restrict__ ow,
                                              __bf16* __restrict__ Mt) {
  const int z = blockIdx.x, h = blockIdx.y, b = blockIdx.z;  // z: 16-row e-slice
  const int tid = threadIdx.x;
  __shared__ float KV[4096];
  __shared__ float OW[16][65];
  const float* kv0 = KVg + (size_t)(b * H_ + h) * 4096;
  for (int i = tid; i < 4096; i += 256) KV[i] = kv0[i];
  for (int i = tid; i < 16 * 64; i += 256) {
    int e = i >> 6, c = i & 63;
    OW[e][c] = ow[(size_t)(z * 16 + e) * HD_ + h * 64 + c];
  }
  __syncthreads();
  for (int i = tid; i < 1024; i += 256) {
    int d = i >> 4, e = i & 15;
    float s = 0.f;
#pragma unroll
    for (int c = 0; c < 64; ++c) s += KV[d * 64 + c] * OW[e][c];
    Mt[(size_t)(b * 64 + z * 16 + e) * HD_ + h * 64 + d] = (__bf16)(s * (1.0f / N_));
  }
}

// ---------------- K3: out = LN(Q) @ Mt^T + o_b/N ----------------
__global__ __launch_bounds__(256) void k3_out(
    const __bf16* __restrict__ vb, const __bf16* __restrict__ wqb,
    const float* __restrict__ qbias, const float* __restrict__ lnqw,
    const float* __restrict__ lnqb, const __bf16* __restrict__ Mt,
    const float* __restrict__ obias, float* __restrict__ out) {
  const int nt = blockIdx.x, b = blockIdx.y;
  const int tid = threadIdx.x;
  const int w = tid >> 6, lane = tid & 63;
  const int l15 = lane & 15, g = lane >> 4;
  __shared__ __bf16 Q[64][HD_ + 8];  // row stride 520 -> 16B-aligned
  const int row0 = nt * 64;

  bf16x8 av[4][2];
#pragma unroll
  for (int m = 0; m < 4; ++m)
#pragma unroll
    for (int kk = 0; kk < 2; ++kk)
      av[m][kk] = *reinterpret_cast<const bf16x8*>(
          vb + ((size_t)b * N_ + row0 + m * 16 + l15) * CIN_ + kk * 32 + g * 8);

#pragma unroll
  for (int hh = 0; hh < 2; ++hh) {
    const int h = w * 2 + hh;
    float qb[4], lw[4], lb[4];
#pragma unroll
    for (int c = 0; c < 4; ++c) {
      const int col = h * 64 + c * 16 + l15;
      qb[c] = qbias[col]; lw[c] = lnqw[col]; lb[c] = lnqb[col];
    }
    f32x4 acc[4][4];
    proj16(av, wqb + (size_t)h * 64 * CIN_, l15, g, acc);
#pragma unroll
    for (int m = 0; m < 4; ++m)
#pragma unroll
      for (int c = 0; c < 4; ++c)
#pragma unroll
        for (int r = 0; r < 4; ++r) acc[m][c][r] += qb[c];
    ln_head(acc, lw, lb);
#pragma unroll
    for (int m = 0; m < 4; ++m)
#pragma unroll
      for (int c = 0; c < 4; ++c)
#pragma unroll
        for (int r = 0; r < 4; ++r)
          Q[m * 16 + g * 4 + r][h * 64 + c * 16 + l15] = (__bf16)acc[m][c][r];
  }
  __syncthreads();

  f32x4 acc2[4];
  const f32x4 z4 = {0.f, 0.f, 0.f, 0.f};
#pragma unroll
  for (int et = 0; et < 4; ++et) acc2[et] = z4;
  for (int kk = 0; kk < 16; ++kk) {
    bf16x8 aq = *reinterpret_cast<const bf16x8*>(&Q[w * 16 + l15][kk * 32 + g * 8]);
#pragma unroll
    for (int et = 0; et < 4; ++et) {
      bf16x8 bm = *reinterpret_cast<const bf16x8*>(
          Mt + (size_t)(b * 64 + et * 16 + l15) * HD_ + kk * 32 + g * 8);
      acc2[et] = __builtin_amdgcn_mfma_f32_16x16x32_bf16(aq, bm, acc2[et], 0, 0, 0);
    }
  }
#pragma unroll
  for (int et = 0; et < 4; ++et) {
    const float ob = obias[et * 16 + l15] * (1.0f / N_);
#pragma unroll
    for (int r = 0; r < 4; ++r)
      out[((size_t)b * N_ + row0 + w * 16 + g * 4 + r) * 64 + et * 16 + l15] =
          acc2[et][r] + ob;
  }
}

// ---------------- launch ----------------
extern "C" void kernel_launch(void* const* d_in, const int* in_sizes, int n_in,
                              void* d_out, int out_size, void* d_ws, size_t ws_size,
                              hipStream_t stream) {
  const float* v     = (const float*)d_in[0];
  const float* Wq_w  = (const float*)d_in[1];
  const float* Wq_b  = (const float*)d_in[2];
  const float* Wk_w  = (const float*)d_in[3];
  const float* Wk_b  = (const float*)d_in[4];
  const float* Wv_w  = (const float*)d_in[5];
  const float* Wv_b  = (const float*)d_in[6];
  const float* lnq_w = (const float*)d_in[7];
  const float* lnq_b = (const float*)d_in[8];
  const float* lnk_w = (const float*)d_in[9];
  const float* lnk_b = (const float*)d_in[10];
  const float* o_w   = (const float*)d_in[11];
  const float* o_b   = (const float*)d_in[12];
  float* out = (float*)d_out;
  char* ws = (char*)d_ws;
  if (ws_size < WS_NEED) return;  // insufficient scratch; fail visibly

  __bf16* vb   = (__bf16*)(ws + OFF_V);
  __bf16* wqb  = (__bf16*)(ws + OFF_WQ);
  __bf16* wkb  = (__bf16*)(ws + OFF_WK);
  __bf16* wvb  = (__bf16*)(ws + OFF_WV);
  __bf16* Mt   = (__bf16*)(ws + OFF_MT);
  float*  part = (float*)(ws + OFF_PART);
  float*  KVg  = (float*)(ws + OFF_KV);

  cast_f32_bf16<<<(B_ * N_ * CIN_ / 4 + 255) / 256, 256, 0, stream>>>(v, vb, B_ * N_ * CIN_ / 4);
  cast_f32_bf16<<<(HD_ * CIN_ / 4 + 255) / 256, 256, 0, stream>>>(Wq_w, wqb, HD_ * CIN_ / 4);
  cast_f32_bf16<<<(HD_ * CIN_ / 4 + 255) / 256, 256, 0, stream>>>(Wk_w, wkb, HD_ * CIN_ / 4);
  cast_f32_bf16<<<(HD_ * CIN_ / 4 + 255) / 256, 256, 0, stream>>>(Wv_w, wvb, HD_ * CIN_ / 4);

  k1_kv<<<dim3(NCH_, H_, B_), 64, 0, stream>>>(vb, wkb, wvb, Wk_b, Wv_b, lnk_w, lnk_b, part);
  k2a_reduce<<<dim3(16, H_, B_), 256, 0, stream>>>(part, KVg);
  k2b_mt<<<dim3(4, H_, B_), 256, 0, stream>>>(KVg, o_w, Mt);
  k3_out<<<dim3(N_ / 64, B_), 256, 0, stream>>>(vb, wqb, Wq_b, lnq_w, lnq_b, Mt, o_b, out);
}

// Round 3
// 70.910 us; speedup vs baseline: 1.1420x; 1.1420x over previous
//
#include <hip/hip_runtime.h>
#include <hip/hip_bf16.h>

#define B_   4
#define N_   8192
#define CIN_ 64
#define H_   8
#define HD_  512
#define EPS_ 1e-5f

typedef __bf16 bf16x8 __attribute__((ext_vector_type(8)));
typedef __bf16 bf16x4 __attribute__((ext_vector_type(4)));
typedef float  f32x4  __attribute__((ext_vector_type(4)));

// ---------------- workspace layout ----------------
constexpr size_t OFF_V    = 0;
constexpr size_t SZ_V     = (size_t)B_ * N_ * CIN_ * 2;        // 4 MB bf16 v
constexpr size_t OFF_WQ   = OFF_V + SZ_V;
constexpr size_t SZ_W     = (size_t)HD_ * CIN_ * 2;            // 64 KB each
constexpr size_t OFF_WK   = OFF_WQ + SZ_W;
constexpr size_t OFF_WV   = OFF_WK + SZ_W;
constexpr size_t OFF_MT   = OFF_WV + SZ_W;
constexpr size_t SZ_MT    = (size_t)B_ * 64 * HD_ * 2;         // 256 KB bf16 Mt
constexpr size_t OFF_PART = OFF_MT + SZ_MT;
constexpr size_t SZ_PART  = (size_t)B_ * H_ * 16 * 64 * 64 * 4; // 8 MB fp32
constexpr size_t WS_NEED  = OFF_PART + SZ_PART;

// ---------------- DPP 16-lane rotation reduce (VALU-only) ----------------
template <int CTRL>
__device__ __forceinline__ float dpp_radd(float x) {
  union { float f; int i; } u, v;
  u.f = x;
  v.i = __builtin_amdgcn_update_dpp(0, u.i, CTRL, 0xF, 0xF, false);
  return x + v.f;
}
__device__ __forceinline__ float red16(float x) {
  x = dpp_radd<0x121>(x);  // row_ror:1
  x = dpp_radd<0x122>(x);  // row_ror:2
  x = dpp_radd<0x124>(x);  // row_ror:4
  x = dpp_radd<0x128>(x);  // row_ror:8
  return x;
}

// ---------------- prep: all fp32->bf16 casts in one kernel ----------------
__global__ __launch_bounds__(256) void prep_cast(
    const float* __restrict__ v, const float* __restrict__ wq,
    const float* __restrict__ wk, const float* __restrict__ wv,
    __bf16* __restrict__ vb, __bf16* __restrict__ wqb,
    __bf16* __restrict__ wkb, __bf16* __restrict__ wvb) {
  const int NV4 = B_ * N_ * CIN_ / 4;   // 524288
  const int NW4 = HD_ * CIN_ / 4;       // 8192
  int i = blockIdx.x * 256 + threadIdx.x;  // grid sized exactly
  const float* src; __bf16* dst; int j;
  if (i < NV4)                { src = v;  dst = vb;  j = i; }
  else if (i < NV4 + NW4)     { src = wq; dst = wqb; j = i - NV4; }
  else if (i < NV4 + 2 * NW4) { src = wk; dst = wkb; j = i - NV4 - NW4; }
  else                        { src = wv; dst = wvb; j = i - NV4 - 2 * NW4; }
  const float4 f = reinterpret_cast<const float4*>(src)[j];
  bf16x4 o;
  o[0] = (__bf16)f.x; o[1] = (__bf16)f.y; o[2] = (__bf16)f.z; o[3] = (__bf16)f.w;
  reinterpret_cast<bf16x4*>(dst)[j] = o;
}

// ---------------- K1: per-(b,h,chunk) KV partial, 4 waves/block ----------------
// Each wave: 128 rows (2 tiles of 64). Block reduces 4 waves' KV -> 1 partial.
// NOTE: explicit __syncthreads() between LDS writes (bf16x4*) and reads
// (bf16x8*) — differently-typed LDS accesses must not rely on program order
// (TBAA may reorder); round-2 removed these and failed with small error.
__global__ __launch_bounds__(256, 2) void k1_kv(
    const __bf16* __restrict__ vb, const __bf16* __restrict__ wkb,
    const __bf16* __restrict__ wvb, const float* __restrict__ kbias,
    const float* __restrict__ vbias, const float* __restrict__ lnkw,
    const float* __restrict__ lnkb, float* __restrict__ part) {
  const int ch = blockIdx.x, h = blockIdx.y, b = blockIdx.z;
  const int tid = threadIdx.x, w = tid >> 6, lane = tid & 63;
  const int l15 = lane & 15, g = lane >> 4;
  __shared__ alignas(16) char smem[73728];
  __bf16 (*Kt)[72] = reinterpret_cast<__bf16(*)[72]>(smem + w * 18432);          // [d][n]
  __bf16 (*Vt)[72] = reinterpret_cast<__bf16(*)[72]>(smem + w * 18432 + 9216);   // [e][n]

  const f32x4 z4 = {0.f, 0.f, 0.f, 0.f};
  f32x4 kv[4][4];
#pragma unroll
  for (int i = 0; i < 4; ++i)
#pragma unroll
    for (int j = 0; j < 4; ++j) kv[i][j] = z4;

  float kb[4], vbi[4], lw[4], lb[4];
#pragma unroll
  for (int c = 0; c < 4; ++c) {
    const int col = h * 64 + c * 16 + l15;
    kb[c] = kbias[col]; vbi[c] = vbias[col];
    lw[c] = lnkw[col];  lb[c] = lnkb[col];
  }
  // hoisted weight B-frags
  bf16x8 wkf[4][2], wvf[4][2];
#pragma unroll
  for (int c = 0; c < 4; ++c)
#pragma unroll
    for (int kk = 0; kk < 2; ++kk) {
      wkf[c][kk] = *reinterpret_cast<const bf16x8*>(
          wkb + (size_t)(h * 64 + c * 16 + l15) * CIN_ + kk * 32 + g * 8);
      wvf[c][kk] = *reinterpret_cast<const bf16x8*>(
          wvb + (size_t)(h * 64 + c * 16 + l15) * CIN_ + kk * 32 + g * 8);
    }

  for (int t = 0; t < 2; ++t) {
    const int row0 = ch * 512 + w * 128 + t * 64;
    bf16x8 av[4][2];
#pragma unroll
    for (int m = 0; m < 4; ++m)
#pragma unroll
      for (int kk = 0; kk < 2; ++kk)
        av[m][kk] = *reinterpret_cast<const bf16x8*>(
            vb + ((size_t)b * N_ + row0 + m * 16 + l15) * CIN_ + kk * 32 + g * 8);

    // ---- K proj + bias + LN -> Kt (m-pairs to cap VGPR) ----
#pragma unroll
    for (int mp = 0; mp < 2; ++mp) {
      f32x4 acc[2][4];
#pragma unroll
      for (int mi = 0; mi < 2; ++mi)
#pragma unroll
        for (int c = 0; c < 4; ++c) {
          f32x4 a = z4;
          a = __builtin_amdgcn_mfma_f32_16x16x32_bf16(av[mp * 2 + mi][0], wkf[c][0], a, 0, 0, 0);
          a = __builtin_amdgcn_mfma_f32_16x16x32_bf16(av[mp * 2 + mi][1], wkf[c][1], a, 0, 0, 0);
          acc[mi][c] = a;
        }
#pragma unroll
      for (int mi = 0; mi < 2; ++mi) {
        const int m = mp * 2 + mi;
        float s[4] = {0, 0, 0, 0}, ss[4] = {0, 0, 0, 0};
#pragma unroll
        for (int c = 0; c < 4; ++c)
#pragma unroll
          for (int r = 0; r < 4; ++r) {
            float x = acc[mi][c][r] + kb[c];
            acc[mi][c][r] = x;
            s[r] += x; ss[r] += x * x;
          }
#pragma unroll
        for (int r = 0; r < 4; ++r) {
          const float S = red16(s[r]), Q = red16(ss[r]);
          const float mu = S * (1.f / 64.f);
          const float var = Q * (1.f / 64.f) - mu * mu;
          const float rstd = rsqrtf(var + EPS_);
#pragma unroll
          for (int c = 0; c < 4; ++c)
            acc[mi][c][r] = (acc[mi][c][r] - mu) * rstd * lw[c] + lb[c];
        }
#pragma unroll
        for (int c = 0; c < 4; ++c) {
          bf16x4 p;
#pragma unroll
          for (int r = 0; r < 4; ++r) p[r] = (__bf16)acc[mi][c][r];
          *reinterpret_cast<bf16x4*>(&Kt[c * 16 + l15][m * 16 + g * 4]) = p;
        }
      }
    }
    // ---- V proj + bias -> Vt ----
#pragma unroll
    for (int mp = 0; mp < 2; ++mp) {
      f32x4 acc[2][4];
#pragma unroll
      for (int mi = 0; mi < 2; ++mi)
#pragma unroll
        for (int c = 0; c < 4; ++c) {
          f32x4 a = z4;
          a = __builtin_amdgcn_mfma_f32_16x16x32_bf16(av[mp * 2 + mi][0], wvf[c][0], a, 0, 0, 0);
          a = __builtin_amdgcn_mfma_f32_16x16x32_bf16(av[mp * 2 + mi][1], wvf[c][1], a, 0, 0, 0);
          acc[mi][c] = a;
        }
#pragma unroll
      for (int mi = 0; mi < 2; ++mi) {
        const int m = mp * 2 + mi;
#pragma unroll
        for (int c = 0; c < 4; ++c) {
          bf16x4 p;
#pragma unroll
          for (int r = 0; r < 4; ++r) p[r] = (__bf16)(acc[mi][c][r] + vbi[c]);
          *reinterpret_cast<bf16x4*>(&Vt[c * 16 + l15][m * 16 + g * 4]) = p;
        }
      }
    }

    __syncthreads();  // LDS writes (bf16x4) -> reads (bf16x8): enforce order

    // ---- KV accumulate ----
    bf16x8 va[4][2];
#pragma unroll
    for (int et = 0; et < 4; ++et)
#pragma unroll
      for (int nk = 0; nk < 2; ++nk)
        va[et][nk] = *reinterpret_cast<const bf16x8*>(&Vt[et * 16 + l15][nk * 32 + g * 8]);
#pragma unroll
    for (int dt = 0; dt < 4; ++dt) {
      bf16x8 ka[2];
#pragma unroll
      for (int nk = 0; nk < 2; ++nk)
        ka[nk] = *reinterpret_cast<const bf16x8*>(&Kt[dt * 16 + l15][nk * 32 + g * 8]);
#pragma unroll
      for (int et = 0; et < 4; ++et) {
        kv[dt][et] = __builtin_amdgcn_mfma_f32_16x16x32_bf16(ka[0], va[et][0], kv[dt][et], 0, 0, 0);
        kv[dt][et] = __builtin_amdgcn_mfma_f32_16x16x32_bf16(ka[1], va[et][1], kv[dt][et], 0, 0, 0);
      }
    }

    __syncthreads();  // reads complete before next t's writes
  }

  // ---- in-block reduction: 4 waves' KV -> one partial (stored [e][d]) ----
  float* red = reinterpret_cast<float*>(smem + w * 17408);  // [64][68] padded
#pragma unroll
  for (int dt = 0; dt < 4; ++dt)
#pragma unroll
    for (int et = 0; et < 4; ++et)
      *reinterpret_cast<f32x4*>(red + (et * 16 + l15) * 68 + dt * 16 + g * 4) = kv[dt][et];
  __syncthreads();
  float* p0 = part + (size_t)((b * H_ + h) * 16 + ch) * 4096;
#pragma unroll
  for (int k = 0; k < 4; ++k) {
    const int idx4 = tid + k * 256;           // f32x4 index
    const int e = idx4 >> 4, d = (idx4 & 15) * 4;
    f32x4 sum = *reinterpret_cast<const f32x4*>(
        reinterpret_cast<const float*>(smem) + e * 68 + d);
#pragma unroll
    for (int ww = 1; ww < 4; ++ww)
      sum += *reinterpret_cast<const f32x4*>(
          reinterpret_cast<const float*>(smem + ww * 17408) + e * 68 + d);
    *reinterpret_cast<f32x4*>(p0 + idx4 * 4) = sum;
  }
}

// ---------------- K2: reduce partials + Mt[b][E][h*64+d] = (KV @ ow_h^T)/N ----
__global__ __launch_bounds__(256) void k2_mt(const float* __restrict__ part,
                                             const float* __restrict__ ow,
                                             __bf16* __restrict__ Mt) {
  const int h = blockIdx.x, b = blockIdx.y;
  const int tid = threadIdx.x;
  __shared__ float KVt[64][64];  // [e][d]  (= KV[d][e])
  __shared__ float OWl[64][64];  // [E][c]
  const float* p0 = part + (size_t)((b * H_ + h) * 16) * 4096;
  for (int i = tid; i < 4096; i += 256) {
    float s = 0.f;
#pragma unroll
    for (int c = 0; c < 16; ++c) s += p0[(size_t)c * 4096 + i];
    (&KVt[0][0])[i] = s;
  }
  for (int i = tid; i < 4096; i += 256) {
    int E = i >> 6, c = i & 63;
    OWl[E][c] = ow[(size_t)E * HD_ + h * 64 + c];
  }
  __syncthreads();
  for (int i = tid; i < 4096; i += 256) {
    int E = i >> 6, d = i & 63;   // E wave-uniform, d per-lane
    float s = 0.f;
#pragma unroll
    for (int c = 0; c < 64; ++c) s += KVt[c][d] * OWl[E][c];
    Mt[(size_t)(b * 64 + E) * HD_ + h * 64 + d] = (__bf16)(s * (1.0f / N_));
  }
}

// ---------------- K3: out = LN(Q) @ Mt^T + o_b/N (transposed Q-proj) ----------
__global__ __launch_bounds__(256, 2) void k3_out(
    const __bf16* __restrict__ vb, const __bf16* __restrict__ wqb,
    const float* __restrict__ qbias, const float* __restrict__ lnqw,
    const float* __restrict__ lnqb, const __bf16* __restrict__ Mt,
    const float* __restrict__ obias, float* __restrict__ out) {
  const int nt = blockIdx.x, b = blockIdx.y;
  const int tid = threadIdx.x, w = tid >> 6, lane = tid & 63;
  const int l15 = lane & 15, g = lane >> 4;
  __shared__ __bf16 Qt[64][520];  // [n][j]
  const int row0 = nt * 64;
  const f32x4 z4 = {0.f, 0.f, 0.f, 0.f};

  // v as B-frags: lane = n-col, k = cin contiguous
  bf16x8 bv[4][2];
#pragma unroll
  for (int c = 0; c < 4; ++c)
#pragma unroll
    for (int kk = 0; kk < 2; ++kk)
      bv[c][kk] = *reinterpret_cast<const bf16x8*>(
          vb + ((size_t)b * N_ + row0 + c * 16 + l15) * CIN_ + kk * 32 + g * 8);

#pragma unroll
  for (int hh = 0; hh < 2; ++hh) {
    const int h = w * 2 + hh;
    bf16x8 aw[4][2];  // Wq rows as A-frags
#pragma unroll
    for (int mj = 0; mj < 4; ++mj)
#pragma unroll
      for (int kk = 0; kk < 2; ++kk)
        aw[mj][kk] = *reinterpret_cast<const bf16x8*>(
            wqb + (size_t)(h * 64 + mj * 16 + l15) * CIN_ + kk * 32 + g * 8);
    f32x4 qb4[4], lw4[4], lb4[4];
#pragma unroll
    for (int mj = 0; mj < 4; ++mj) {
      const int base = h * 64 + mj * 16 + g * 4;
      qb4[mj] = *reinterpret_cast<const f32x4*>(qbias + base);
      lw4[mj] = *reinterpret_cast<const f32x4*>(lnqw + base);
      lb4[mj] = *reinterpret_cast<const f32x4*>(lnqb + base);
    }
    // transposed proj: D[j-row, n-col]
    f32x4 acc[4][4];
#pragma unroll
    for (int mj = 0; mj < 4; ++mj)
#pragma unroll
      for (int c = 0; c < 4; ++c) {
        f32x4 a = z4;
        a = __builtin_amdgcn_mfma_f32_16x16x32_bf16(aw[mj][0], bv[c][0], a, 0, 0, 0);
        a = __builtin_amdgcn_mfma_f32_16x16x32_bf16(aw[mj][1], bv[c][1], a, 0, 0, 0);
        acc[mj][c] = a;
      }
    // bias; LN per n-col: 16 lane-local values + xor16/xor32
#pragma unroll
    for (int c = 0; c < 4; ++c) {
      float s = 0.f, ss = 0.f;
#pragma unroll
      for (int mj = 0; mj < 4; ++mj)
#pragma unroll
        for (int r = 0; r < 4; ++r) {
          float x = acc[mj][c][r] + qb4[mj][r];
          acc[mj][c][r] = x;
          s += x; ss += x * x;
        }
      s += __shfl_xor(s, 16); ss += __shfl_xor(ss, 16);
      s += __shfl_xor(s, 32); ss += __shfl_xor(ss, 32);
      const float mu = s * (1.f / 64.f);
      const float var = ss * (1.f / 64.f) - mu * mu;
      const float rstd = rsqrtf(var + EPS_);
#pragma unroll
      for (int mj = 0; mj < 4; ++mj)
#pragma unroll
        for (int r = 0; r < 4; ++r)
          acc[mj][c][r] = (acc[mj][c][r] - mu) * rstd * lw4[mj][r] + lb4[mj][r];
    }
    // vectorized transpose store: lane's 4 j-contiguous values
#pragma unroll
    for (int mj = 0; mj < 4; ++mj)
#pragma unroll
      for (int c = 0; c < 4; ++c) {
        bf16x4 p;
#pragma unroll
        for (int r = 0; r < 4; ++r) p[r] = (__bf16)acc[mj][c][r];
        *reinterpret_cast<bf16x4*>(&Qt[c * 16 + l15][h * 64 + mj * 16 + g * 4]) = p;
      }
  }
  __syncthreads();

  // final GEMM: out[64 x 64] = Qt[64 x 512] @ Mt[b]^T
  f32x4 acc2[4];
#pragma unroll
  for (int et = 0; et < 4; ++et) acc2[et] = z4;
  for (int kk = 0; kk < 16; ++kk) {
    bf16x8 aq = *reinterpret_cast<const bf16x8*>(&Qt[w * 16 + l15][kk * 32 + g * 8]);
#pragma unroll
    for (int et = 0; et < 4; ++et) {
      bf16x8 bm = *reinterpret_cast<const bf16x8*>(
          Mt + (size_t)(b * 64 + et * 16 + l15) * HD_ + kk * 32 + g * 8);
      acc2[et] = __builtin_amdgcn_mfma_f32_16x16x32_bf16(aq, bm, acc2[et], 0, 0, 0);
    }
  }
#pragma unroll
  for (int et = 0; et < 4; ++et) {
    const float ob = obias[et * 16 + l15] * (1.0f / N_);
#pragma unroll
    for (int r = 0; r < 4; ++r)
      out[((size_t)b * N_ + row0 + w * 16 + g * 4 + r) * 64 + et * 16 + l15] =
          acc2[et][r] + ob;
  }
}

// ---------------- launch ----------------
extern "C" void kernel_launch(void* const* d_in, const int* in_sizes, int n_in,
                              void* d_out, int out_size, void* d_ws, size_t ws_size,
                              hipStream_t stream) {
  const float* v     = (const float*)d_in[0];
  const float* Wq_w  = (const float*)d_in[1];
  const float* Wq_b  = (const float*)d_in[2];
  const float* Wk_w  = (const float*)d_in[3];
  const float* Wk_b  = (const float*)d_in[4];
  const float* Wv_w  = (const float*)d_in[5];
  const float* Wv_b  = (const float*)d_in[6];
  const float* lnq_w = (const float*)d_in[7];
  const float* lnq_b = (const float*)d_in[8];
  const float* lnk_w = (const float*)d_in[9];
  const float* lnk_b = (const float*)d_in[10];
  const float* o_w   = (const float*)d_in[11];
  const float* o_b   = (const float*)d_in[12];
  float* out = (float*)d_out;
  char* ws = (char*)d_ws;
  if (ws_size < WS_NEED) return;

  __bf16* vb   = (__bf16*)(ws + OFF_V);
  __bf16* wqb  = (__bf16*)(ws + OFF_WQ);
  __bf16* wkb  = (__bf16*)(ws + OFF_WK);
  __bf16* wvb  = (__bf16*)(ws + OFF_WV);
  __bf16* Mt   = (__bf16*)(ws + OFF_MT);
  float*  part = (float*)(ws + OFF_PART);

  const int NTOT4 = B_ * N_ * CIN_ / 4 + 3 * (HD_ * CIN_ / 4);  // 548864
  prep_cast<<<NTOT4 / 256, 256, 0, stream>>>(v, Wq_w, Wk_w, Wv_w, vb, wqb, wkb, wvb);
  k1_kv<<<dim3(16, H_, B_), 256, 0, stream>>>(vb, wkb, wvb, Wk_b, Wv_b, lnk_w, lnk_b, part);
  k2_mt<<<dim3(H_, B_), 256, 0, stream>>>(part, o_w, Mt);
  k3_out<<<dim3(N_ / 64, B_), 256, 0, stream>>>(vb, wqb, Wq_b, lnq_w, lnq_b, Mt, o_b, out);
}

// Round 4
// 61.263 us; speedup vs baseline: 1.3218x; 1.1575x over previous
//
#include <hip/hip_runtime.h>
#include <hip/hip_bf16.h>

#define B_   4
#define N_   8192
#define CIN_ 64
#define H_   8
#define HD_  512
#define EPS_ 1e-5f
#define NCH_ 32   // k1 chunks per (b,h); each block covers 256 rows

typedef __bf16 bf16x8 __attribute__((ext_vector_type(8)));
typedef __bf16 bf16x4 __attribute__((ext_vector_type(4)));
typedef float  f32x4  __attribute__((ext_vector_type(4)));

// ---------------- workspace layout ----------------
constexpr size_t OFF_V    = 0;
constexpr size_t SZ_V     = (size_t)B_ * N_ * CIN_ * 2;           // 4 MB bf16 v
constexpr size_t OFF_WQ   = OFF_V + SZ_V;
constexpr size_t SZ_W     = (size_t)HD_ * CIN_ * 2;               // 64 KB each
constexpr size_t OFF_WK   = OFF_WQ + SZ_W;
constexpr size_t OFF_WV   = OFF_WK + SZ_W;
constexpr size_t OFF_MT   = OFF_WV + SZ_W;
constexpr size_t SZ_MT    = (size_t)B_ * 64 * HD_ * 4;            // 512 KB fp32 Mt
constexpr size_t OFF_KVG  = OFF_MT + SZ_MT;
constexpr size_t SZ_KVG   = (size_t)B_ * H_ * 4096 * 4;           // 512 KB fp32
constexpr size_t OFF_PART = OFF_KVG + SZ_KVG;
constexpr size_t SZ_PART  = (size_t)B_ * H_ * NCH_ * 4096 * 4;    // 16 MB fp32
constexpr size_t WS_NEED  = OFF_PART + SZ_PART;

// ---------------- DPP 16-lane rotation reduce (VALU-only) ----------------
template <int CTRL>
__device__ __forceinline__ float dpp_radd(float x) {
  union { float f; int i; } u, v;
  u.f = x;
  v.i = __builtin_amdgcn_update_dpp(0, u.i, CTRL, 0xF, 0xF, false);
  return x + v.f;
}
__device__ __forceinline__ float red16(float x) {
  x = dpp_radd<0x121>(x);  // row_ror:1
  x = dpp_radd<0x122>(x);  // row_ror:2
  x = dpp_radd<0x124>(x);  // row_ror:4
  x = dpp_radd<0x128>(x);  // row_ror:8
  return x;
}

// ---------------- prep: all fp32->bf16 casts in one kernel ----------------
__global__ __launch_bounds__(256) void prep_cast(
    const float* __restrict__ v, const float* __restrict__ wq,
    const float* __restrict__ wk, const float* __restrict__ wv,
    __bf16* __restrict__ vb, __bf16* __restrict__ wqb,
    __bf16* __restrict__ wkb, __bf16* __restrict__ wvb) {
  const int NV4 = B_ * N_ * CIN_ / 4;   // 524288
  const int NW4 = HD_ * CIN_ / 4;       // 8192
  int i = blockIdx.x * 256 + threadIdx.x;  // grid sized exactly
  const float* src; __bf16* dst; int j;
  if (i < NV4)                { src = v;  dst = vb;  j = i; }
  else if (i < NV4 + NW4)     { src = wq; dst = wqb; j = i - NV4; }
  else if (i < NV4 + 2 * NW4) { src = wk; dst = wkb; j = i - NV4 - NW4; }
  else                        { src = wv; dst = wvb; j = i - NV4 - 2 * NW4; }
  const float4 f = reinterpret_cast<const float4*>(src)[j];
  bf16x4 o;
  o[0] = (__bf16)f.x; o[1] = (__bf16)f.y; o[2] = (__bf16)f.z; o[3] = (__bf16)f.w;
  reinterpret_cast<bf16x4*>(dst)[j] = o;
}

// ---------------- K1: per-(b,h,chunk) KV partial, 4 waves/block --------------
// Each wave: ONE 64-row tile. Block reduces 4 waves' KV -> 1 partial.
__global__ __launch_bounds__(256, 2) void k1_kv(
    const __bf16* __restrict__ vb, const __bf16* __restrict__ wkb,
    const __bf16* __restrict__ wvb, const float* __restrict__ kbias,
    const float* __restrict__ vbias, const float* __restrict__ lnkw,
    const float* __restrict__ lnkb, float* __restrict__ part) {
  const int ch = blockIdx.x, h = blockIdx.y, b = blockIdx.z;
  const int tid = threadIdx.x, w = tid >> 6, lane = tid & 63;
  const int l15 = lane & 15, g = lane >> 4;
  __shared__ alignas(16) char smem[73728];
  __bf16 (*Kt)[72] = reinterpret_cast<__bf16(*)[72]>(smem + w * 18432);          // [d][n]
  __bf16 (*Vt)[72] = reinterpret_cast<__bf16(*)[72]>(smem + w * 18432 + 9216);   // [e][n]

  const f32x4 z4 = {0.f, 0.f, 0.f, 0.f};
  f32x4 kv[4][4];
#pragma unroll
  for (int i = 0; i < 4; ++i)
#pragma unroll
    for (int j = 0; j < 4; ++j) kv[i][j] = z4;

  float kb[4], vbi[4], lw[4], lb[4];
#pragma unroll
  for (int c = 0; c < 4; ++c) {
    const int col = h * 64 + c * 16 + l15;
    kb[c] = kbias[col]; vbi[c] = vbias[col];
    lw[c] = lnkw[col];  lb[c] = lnkb[col];
  }
  bf16x8 wkf[4][2], wvf[4][2];
#pragma unroll
  for (int c = 0; c < 4; ++c)
#pragma unroll
    for (int kk = 0; kk < 2; ++kk) {
      wkf[c][kk] = *reinterpret_cast<const bf16x8*>(
          wkb + (size_t)(h * 64 + c * 16 + l15) * CIN_ + kk * 32 + g * 8);
      wvf[c][kk] = *reinterpret_cast<const bf16x8*>(
          wvb + (size_t)(h * 64 + c * 16 + l15) * CIN_ + kk * 32 + g * 8);
    }

  const int row0 = ch * 256 + w * 64;
  bf16x8 av[4][2];
#pragma unroll
  for (int m = 0; m < 4; ++m)
#pragma unroll
    for (int kk = 0; kk < 2; ++kk)
      av[m][kk] = *reinterpret_cast<const bf16x8*>(
          vb + ((size_t)b * N_ + row0 + m * 16 + l15) * CIN_ + kk * 32 + g * 8);

  // ---- K proj + bias + LN -> Kt (m-pairs to cap VGPR) ----
#pragma unroll
  for (int mp = 0; mp < 2; ++mp) {
    f32x4 acc[2][4];
#pragma unroll
    for (int mi = 0; mi < 2; ++mi)
#pragma unroll
      for (int c = 0; c < 4; ++c) {
        f32x4 a = z4;
        a = __builtin_amdgcn_mfma_f32_16x16x32_bf16(av[mp * 2 + mi][0], wkf[c][0], a, 0, 0, 0);
        a = __builtin_amdgcn_mfma_f32_16x16x32_bf16(av[mp * 2 + mi][1], wkf[c][1], a, 0, 0, 0);
        acc[mi][c] = a;
      }
#pragma unroll
    for (int mi = 0; mi < 2; ++mi) {
      const int m = mp * 2 + mi;
      float s[4] = {0, 0, 0, 0}, ss[4] = {0, 0, 0, 0};
#pragma unroll
      for (int c = 0; c < 4; ++c)
#pragma unroll
        for (int r = 0; r < 4; ++r) {
          float x = acc[mi][c][r] + kb[c];
          acc[mi][c][r] = x;
          s[r] += x; ss[r] += x * x;
        }
#pragma unroll
      for (int r = 0; r < 4; ++r) {
        const float S = red16(s[r]), Q = red16(ss[r]);
        const float mu = S * (1.f / 64.f);
        const float var = Q * (1.f / 64.f) - mu * mu;
        const float rstd = rsqrtf(var + EPS_);
#pragma unroll
        for (int c = 0; c < 4; ++c)
          acc[mi][c][r] = (acc[mi][c][r] - mu) * rstd * lw[c] + lb[c];
      }
#pragma unroll
      for (int c = 0; c < 4; ++c) {
        bf16x4 p;
#pragma unroll
        for (int r = 0; r < 4; ++r) p[r] = (__bf16)acc[mi][c][r];
        *reinterpret_cast<bf16x4*>(&Kt[c * 16 + l15][m * 16 + g * 4]) = p;
      }
    }
  }
  // ---- V proj + bias -> Vt ----
#pragma unroll
  for (int mp = 0; mp < 2; ++mp) {
    f32x4 acc[2][4];
#pragma unroll
    for (int mi = 0; mi < 2; ++mi)
#pragma unroll
      for (int c = 0; c < 4; ++c) {
        f32x4 a = z4;
        a = __builtin_amdgcn_mfma_f32_16x16x32_bf16(av[mp * 2 + mi][0], wvf[c][0], a, 0, 0, 0);
        a = __builtin_amdgcn_mfma_f32_16x16x32_bf16(av[mp * 2 + mi][1], wvf[c][1], a, 0, 0, 0);
        acc[mi][c] = a;
      }
#pragma unroll
    for (int mi = 0; mi < 2; ++mi) {
      const int m = mp * 2 + mi;
#pragma unroll
      for (int c = 0; c < 4; ++c) {
        bf16x4 p;
#pragma unroll
        for (int r = 0; r < 4; ++r) p[r] = (__bf16)(acc[mi][c][r] + vbi[c]);
        *reinterpret_cast<bf16x4*>(&Vt[c * 16 + l15][m * 16 + g * 4]) = p;
      }
    }
  }

  __syncthreads();  // LDS writes -> reads: enforce order (R2 lesson)

  // ---- KV accumulate ----
  bf16x8 va[4][2];
#pragma unroll
  for (int et = 0; et < 4; ++et)
#pragma unroll
    for (int nk = 0; nk < 2; ++nk)
      va[et][nk] = *reinterpret_cast<const bf16x8*>(&Vt[et * 16 + l15][nk * 32 + g * 8]);
#pragma unroll
  for (int dt = 0; dt < 4; ++dt) {
    bf16x8 ka[2];
#pragma unroll
    for (int nk = 0; nk < 2; ++nk)
      ka[nk] = *reinterpret_cast<const bf16x8*>(&Kt[dt * 16 + l15][nk * 32 + g * 8]);
#pragma unroll
    for (int et = 0; et < 4; ++et) {
      kv[dt][et] = __builtin_amdgcn_mfma_f32_16x16x32_bf16(ka[0], va[et][0], kv[dt][et], 0, 0, 0);
      kv[dt][et] = __builtin_amdgcn_mfma_f32_16x16x32_bf16(ka[1], va[et][1], kv[dt][et], 0, 0, 0);
    }
  }

  __syncthreads();  // all reads done before red overwrites Kt/Vt

  // ---- in-block reduction: 4 waves' KV -> one partial (stored [e][d]) ----
  float* red = reinterpret_cast<float*>(smem + w * 17408);  // [64][68] padded
#pragma unroll
  for (int dt = 0; dt < 4; ++dt)
#pragma unroll
    for (int et = 0; et < 4; ++et)
      *reinterpret_cast<f32x4*>(red + (et * 16 + l15) * 68 + dt * 16 + g * 4) = kv[dt][et];
  __syncthreads();
  float* p0 = part + (size_t)((b * H_ + h) * NCH_ + ch) * 4096;
#pragma unroll
  for (int k = 0; k < 4; ++k) {
    const int idx4 = tid + k * 256;           // f32x4 index
    const int e = idx4 >> 4, d = (idx4 & 15) * 4;
    f32x4 sum = *reinterpret_cast<const f32x4*>(
        reinterpret_cast<const float*>(smem) + e * 68 + d);
#pragma unroll
    for (int ww = 1; ww < 4; ++ww)
      sum += *reinterpret_cast<const f32x4*>(
          reinterpret_cast<const float*>(smem + ww * 17408) + e * 68 + d);
    *reinterpret_cast<f32x4*>(p0 + idx4 * 4) = sum;
  }
}

// ---------------- K2a: parallel tree-reduce partials -> KVg ----------------
__global__ __launch_bounds__(256) void k2a_reduce(const float* __restrict__ part,
                                                 float* __restrict__ KVg) {
  const int s = blockIdx.x, h = blockIdx.y, b = blockIdx.z;  // s: 0..15
  const int idx = s * 256 + threadIdx.x;
  const float* p0 = part + (size_t)((b * H_ + h) * NCH_) * 4096 + idx;
  float acc = 0.f;
#pragma unroll 8
  for (int ch = 0; ch < NCH_; ++ch) acc += p0[(size_t)ch * 4096];
  KVg[(size_t)(b * H_ + h) * 4096 + idx] = acc;
}

// ---------------- K2b: Mt[b][E][h*64+d] = (KV @ ow_h^T)[d,E]/N  (fp32) -------
__global__ __launch_bounds__(256) void k2b_mt(const float* __restrict__ KVg,
                                              const float* __restrict__ ow,
                                              float* __restrict__ Mt) {
  const int z = blockIdx.x, h = blockIdx.y, b = blockIdx.z;  // z: 16-row E-slice
  const int tid = threadIdx.x;
  __shared__ float KVl[4096];      // [e][d]
  __shared__ float OWl[16][65];
  const float* kv0 = KVg + (size_t)(b * H_ + h) * 4096;
  for (int i = tid; i < 4096; i += 256) KVl[i] = kv0[i];
  for (int i = tid; i < 16 * 64; i += 256) {
    int E = i >> 6, c = i & 63;
    OWl[E][c] = ow[(size_t)(z * 16 + E) * HD_ + h * 64 + c];
  }
  __syncthreads();
  for (int i = tid; i < 1024; i += 256) {
    int E = i >> 6, d = i & 63;
    float s = 0.f;
#pragma unroll
    for (int c = 0; c < 64; ++c) s += KVl[c * 64 + d] * OWl[E][c];
    Mt[(size_t)(b * 64 + z * 16 + E) * HD_ + h * 64 + d] = s * (1.0f / N_);
  }
}

// ---------------- K3: out^T tiles = Mt(hi+lo) @ Qt, Mt-frags in regs ---------
__global__ __launch_bounds__(256, 2) void k3_out(
    const __bf16* __restrict__ vb, const __bf16* __restrict__ wqb,
    const float* __restrict__ qbias, const float* __restrict__ lnqw,
    const float* __restrict__ lnqb, const float* __restrict__ MtF,
    const float* __restrict__ obias, float* __restrict__ out) {
  const int nt = blockIdx.x, b = blockIdx.y;
  const int tid = threadIdx.x, w = tid >> 6, lane = tid & 63;
  const int l15 = lane & 15, g = lane >> 4;
  __shared__ __bf16 Qt[64][520];  // [n][j]
  const int row0 = nt * 64;
  const f32x4 z4 = {0.f, 0.f, 0.f, 0.f};

  // ---- phase 1: transposed Q-proj + LN -> Qt (wave w: heads 2w, 2w+1) ----
  bf16x8 bv[4][2];
#pragma unroll
  for (int c = 0; c < 4; ++c)
#pragma unroll
    for (int kk = 0; kk < 2; ++kk)
      bv[c][kk] = *reinterpret_cast<const bf16x8*>(
          vb + ((size_t)b * N_ + row0 + c * 16 + l15) * CIN_ + kk * 32 + g * 8);

#pragma unroll
  for (int hh = 0; hh < 2; ++hh) {
    const int h = w * 2 + hh;
    bf16x8 aw[4][2];
#pragma unroll
    for (int mj = 0; mj < 4; ++mj)
#pragma unroll
      for (int kk = 0; kk < 2; ++kk)
        aw[mj][kk] = *reinterpret_cast<const bf16x8*>(
            wqb + (size_t)(h * 64 + mj * 16 + l15) * CIN_ + kk * 32 + g * 8);
    f32x4 qb4[4], lw4[4], lb4[4];
#pragma unroll
    for (int mj = 0; mj < 4; ++mj) {
      const int base = h * 64 + mj * 16 + g * 4;
      qb4[mj] = *reinterpret_cast<const f32x4*>(qbias + base);
      lw4[mj] = *reinterpret_cast<const f32x4*>(lnqw + base);
      lb4[mj] = *reinterpret_cast<const f32x4*>(lnqb + base);
    }
    f32x4 acc[4][4];
#pragma unroll
    for (int mj = 0; mj < 4; ++mj)
#pragma unroll
      for (int c = 0; c < 4; ++c) {
        f32x4 a = z4;
        a = __builtin_amdgcn_mfma_f32_16x16x32_bf16(aw[mj][0], bv[c][0], a, 0, 0, 0);
        a = __builtin_amdgcn_mfma_f32_16x16x32_bf16(aw[mj][1], bv[c][1], a, 0, 0, 0);
        acc[mj][c] = a;
      }
#pragma unroll
    for (int c = 0; c < 4; ++c) {
      float s = 0.f, ss = 0.f;
#pragma unroll
      for (int mj = 0; mj < 4; ++mj)
#pragma unroll
        for (int r = 0; r < 4; ++r) {
          float x = acc[mj][c][r] + qb4[mj][r];
          acc[mj][c][r] = x;
          s += x; ss += x * x;
        }
      s += __shfl_xor(s, 16); ss += __shfl_xor(ss, 16);
      s += __shfl_xor(s, 32); ss += __shfl_xor(ss, 32);
      const float mu = s * (1.f / 64.f);
      const float var = ss * (1.f / 64.f) - mu * mu;
      const float rstd = rsqrtf(var + EPS_);
#pragma unroll
      for (int mj = 0; mj < 4; ++mj)
#pragma unroll
        for (int r = 0; r < 4; ++r)
          acc[mj][c][r] = (acc[mj][c][r] - mu) * rstd * lw4[mj][r] + lb4[mj][r];
    }
#pragma unroll
    for (int mj = 0; mj < 4; ++mj)
#pragma unroll
      for (int c = 0; c < 4; ++c) {
        bf16x4 p;
#pragma unroll
        for (int r = 0; r < 4; ++r) p[r] = (__bf16)acc[mj][c][r];
        *reinterpret_cast<bf16x4*>(&Qt[c * 16 + l15][h * 64 + mj * 16 + g * 4]) = p;
      }
  }

  // ---- phase 2: hoist Mt A-frags (fp32 -> bf16 hi+lo) for E-slice w*16.. ----
  bf16x8 mhi[16], mlo[16];
  {
    const float* mrow = MtF + ((size_t)b * 64 + w * 16 + l15) * HD_ + g * 8;
#pragma unroll
    for (int kk = 0; kk < 16; ++kk) {
      const f32x4 x0 = *reinterpret_cast<const f32x4*>(mrow + kk * 32);
      const f32x4 x1 = *reinterpret_cast<const f32x4*>(mrow + kk * 32 + 4);
      bf16x8 hi, lo;
#pragma unroll
      for (int r = 0; r < 4; ++r) {
        hi[r] = (__bf16)x0[r];     lo[r] = (__bf16)(x0[r] - (float)hi[r]);
        hi[4 + r] = (__bf16)x1[r]; lo[4 + r] = (__bf16)(x1[r] - (float)hi[4 + r]);
      }
      mhi[kk] = hi; mlo[kk] = lo;
    }
  }
  __syncthreads();

  // ---- final GEMM: out^T[E-slice, n] = (Mhi+Mlo) @ Qt^T, Qt streamed ----
  f32x4 acc2[4];
#pragma unroll
  for (int et = 0; et < 4; ++et) acc2[et] = z4;
  for (int kk = 0; kk < 16; ++kk) {
#pragma unroll
    for (int et = 0; et < 4; ++et) {
      bf16x8 bq = *reinterpret_cast<const bf16x8*>(&Qt[et * 16 + l15][kk * 32 + g * 8]);
      acc2[et] = __builtin_amdgcn_mfma_f32_16x16x32_bf16(mhi[kk], bq, acc2[et], 0, 0, 0);
      acc2[et] = __builtin_amdgcn_mfma_f32_16x16x32_bf16(mlo[kk], bq, acc2[et], 0, 0, 0);
    }
  }
  // D[m=E_local=g*4+r][ncol=n_local=l15]; store f32x4 along E
  f32x4 ob4;
#pragma unroll
  for (int r = 0; r < 4; ++r) ob4[r] = obias[w * 16 + g * 4 + r] * (1.0f / N_);
#pragma unroll
  for (int et = 0; et < 4; ++et) {
    f32x4 res = acc2[et] + ob4;
    *reinterpret_cast<f32x4*>(
        out + ((size_t)b * N_ + row0 + et * 16 + l15) * 64 + w * 16 + g * 4) = res;
  }
}

// ---------------- launch ----------------
extern "C" void kernel_launch(void* const* d_in, const int* in_sizes, int n_in,
                              void* d_out, int out_size, void* d_ws, size_t ws_size,
                              hipStream_t stream) {
  const float* v     = (const float*)d_in[0];
  const float* Wq_w  = (const float*)d_in[1];
  const float* Wq_b  = (const float*)d_in[2];
  const float* Wk_w  = (const float*)d_in[3];
  const float* Wk_b  = (const float*)d_in[4];
  const float* Wv_w  = (const float*)d_in[5];
  const float* Wv_b  = (const float*)d_in[6];
  const float* lnq_w = (const float*)d_in[7];
  const float* lnq_b = (const float*)d_in[8];
  const float* lnk_w = (const float*)d_in[9];
  const float* lnk_b = (const float*)d_in[10];
  const float* o_w   = (const float*)d_in[11];
  const float* o_b   = (const float*)d_in[12];
  float* out = (float*)d_out;
  char* ws = (char*)d_ws;
  if (ws_size < WS_NEED) return;

  __bf16* vb   = (__bf16*)(ws + OFF_V);
  __bf16* wqb  = (__bf16*)(ws + OFF_WQ);
  __bf16* wkb  = (__bf16*)(ws + OFF_WK);
  __bf16* wvb  = (__bf16*)(ws + OFF_WV);
  float*  Mt   = (float*)(ws + OFF_MT);
  float*  KVg  = (float*)(ws + OFF_KVG);
  float*  part = (float*)(ws + OFF_PART);

  const int NTOT4 = B_ * N_ * CIN_ / 4 + 3 * (HD_ * CIN_ / 4);  // 548864
  prep_cast<<<NTOT4 / 256, 256, 0, stream>>>(v, Wq_w, Wk_w, Wv_w, vb, wqb, wkb, wvb);
  k1_kv<<<dim3(NCH_, H_, B_), 256, 0, stream>>>(vb, wkb, wvb, Wk_b, Wv_b, lnk_w, lnk_b, part);
  k2a_reduce<<<dim3(16, H_, B_), 256, 0, stream>>>(part, KVg);
  k2b_mt<<<dim3(4, H_, B_), 256, 0, stream>>>(KVg, o_w, Mt);
  k3_out<<<dim3(N_ / 64, B_), 256, 0, stream>>>(vb, wqb, Wq_b, lnq_w, lnq_b, Mt, o_b, out);
}